// Round 4
// baseline (515.179 us; speedup 1.0000x reference)
//
#include <hip/hip_runtime.h>
#include <hip/hip_bf16.h>

typedef __bf16 bf8 __attribute__((ext_vector_type(8)));
typedef float f4 __attribute__((ext_vector_type(4)));
typedef unsigned short u16;
typedef unsigned int u32;

#define B_ 4
#define P_ 2048
#define D_ 768
#define H_ 12
#define HD_ 64
// scale * log2(e): exp(s*0.125) = exp2(s * 0.18033688)
#define EXPC_ 0.18033688011112042f

typedef const __attribute__((address_space(1))) void gvoid;
typedef __attribute__((address_space(3))) void lvoid;

__device__ __forceinline__ void gl_lds16(const u16* g, u16* l) {
  __builtin_amdgcn_global_load_lds((gvoid*)g, (lvoid*)l, 16, 0, 0);
}

__device__ __forceinline__ u16 f2bf(float f) {  // RNE
  union { float f; u32 u; } c; c.f = f;
  u32 u = c.u;
  u += 0x7fffu + ((u >> 16) & 1u);
  return (u16)(u >> 16);
}

__device__ __forceinline__ float bf2f(u16 v) {
  union { u32 u; float f; } c; c.u = (u32)v << 16; return c.f;
}

__device__ __forceinline__ uint2 pack4(f4 v) {  // truncating 4xf32 -> 4xbf16
  union { float f; u32 u; } a, b, c, d;
  a.f = v[0]; b.f = v[1]; c.f = v[2]; d.f = v[3];
  uint2 r;
  r.x = (a.u >> 16) | (b.u & 0xffff0000u);
  r.y = (c.u >> 16) | (d.u & 0xffff0000u);
  return r;
}

__device__ __forceinline__ f4 unpack4(ushort4 v) {
  f4 r;
  r[0] = bf2f(v.x); r[1] = bf2f(v.y); r[2] = bf2f(v.z); r[3] = bf2f(v.w);
  return r;
}

__device__ __forceinline__ f4 unp2(uint2 u) {
  f4 r;
  r[0] = bf2f((u16)(u.x & 0xffffu)); r[1] = bf2f((u16)(u.x >> 16));
  r[2] = bf2f((u16)(u.y & 0xffffu)); r[3] = bf2f((u16)(u.y >> 16));
  return r;
}

__device__ __forceinline__ bf8 mkbf8(f4 a, f4 b) {
  union { uint4 u; bf8 v; } c;
  uint2 l = pack4(a), h = pack4(b);
  c.u = make_uint4(l.x, l.y, h.x, h.y);
  return c.v;
}

__device__ __forceinline__ f4 mfma16(bf8 a, bf8 b, f4 c) {
  return __builtin_amdgcn_mfma_f32_16x16x32_bf16(a, b, c, 0, 0, 0);
}

#define ZERO44(acc)                    \
  {                                    \
    f4 z_ = {0.f, 0.f, 0.f, 0.f};      \
    for (int i_ = 0; i_ < 4; ++i_)     \
      for (int j_ = 0; j_ < 4; ++j_)   \
        acc[i_][j_] = z_;              \
  }

// ---------------- transpose-cast fp32 (R,C) -> bf16 (C,R) ----------------
__global__ __launch_bounds__(256) void tcast_k(const float* __restrict__ src,
                                               u16* __restrict__ dst, int R, int C) {
  __shared__ float t[32][33];
  int c0 = blockIdx.x * 32, r0 = blockIdx.y * 32;
  int tx = threadIdx.x & 31, ty = threadIdx.x >> 5;
  #pragma unroll
  for (int i = 0; i < 32; i += 8) {
    int r = r0 + ty + i, c = c0 + tx;
    t[ty + i][tx] = (r < R && c < C) ? src[(size_t)r * C + c] : 0.f;
  }
  __syncthreads();
  #pragma unroll
  for (int i = 0; i < 32; i += 8) {
    int c = c0 + ty + i, r = r0 + tx;
    if (c < C && r < R) dst[(size_t)c * R + r] = f2bf(t[tx][ty + i]);
  }
}

// ---------------- layernorm fp32 -> bf16 (LN1) ----------------
__global__ __launch_bounds__(256) void ln_k(const float* __restrict__ x,
                                            const float* __restrict__ g,
                                            const float* __restrict__ b,
                                            u16* __restrict__ out) {
  int row = blockIdx.x;
  const float* xr = x + (size_t)row * D_;
  float v0 = xr[threadIdx.x], v1 = xr[threadIdx.x + 256], v2 = xr[threadIdx.x + 512];
  float s = v0 + v1 + v2;
  float s2 = v0 * v0 + v1 * v1 + v2 * v2;
  #pragma unroll
  for (int o = 32; o > 0; o >>= 1) {
    s += __shfl_down(s, o, 64);
    s2 += __shfl_down(s2, o, 64);
  }
  __shared__ float a[4], a2[4];
  int wv = threadIdx.x >> 6;
  if ((threadIdx.x & 63) == 0) { a[wv] = s; a2[wv] = s2; }
  __syncthreads();
  s = a[0] + a[1] + a[2] + a[3];
  s2 = a2[0] + a2[1] + a2[2] + a2[3];
  float mean = s * (1.f / 768.f);
  float var = s2 * (1.f / 768.f) - mean * mean;
  float rstd = rsqrtf(var + 1e-5f);
  u16* orow = out + (size_t)row * D_;
  float vv[3] = {v0, v1, v2};
  #pragma unroll
  for (int j = 0; j < 3; ++j) {
    int i = threadIdx.x + j * 256;
    orow[i] = f2bf((vv[j] - mean) * rstd * g[i] + b[i]);
  }
}

// ---------------- x2 = x + O0 + O1; hln = LN(x2) (LN2 fused with partial-O sum) ----------------
__global__ __launch_bounds__(256) void ln2add_k(const float* __restrict__ x,
                                                const u16* __restrict__ O0,
                                                const u16* __restrict__ O1,
                                                const float* __restrict__ g,
                                                const float* __restrict__ b,
                                                float* __restrict__ x2,
                                                u16* __restrict__ out) {
  int row = blockIdx.x;
  const float* xr = x + (size_t)row * D_;
  const u16* o0 = O0 + (size_t)row * D_;
  const u16* o1 = O1 + (size_t)row * D_;
  float vv[3];
  #pragma unroll
  for (int j = 0; j < 3; ++j) {
    int i = threadIdx.x + j * 256;
    vv[j] = xr[i] + bf2f(o0[i]) + bf2f(o1[i]);
  }
  float s = vv[0] + vv[1] + vv[2];
  float s2 = vv[0] * vv[0] + vv[1] * vv[1] + vv[2] * vv[2];
  #pragma unroll
  for (int o = 32; o > 0; o >>= 1) {
    s += __shfl_down(s, o, 64);
    s2 += __shfl_down(s2, o, 64);
  }
  __shared__ float a[4], a2[4];
  int wv = threadIdx.x >> 6;
  if ((threadIdx.x & 63) == 0) { a[wv] = s; a2[wv] = s2; }
  __syncthreads();
  s = a[0] + a[1] + a[2] + a[3];
  s2 = a2[0] + a2[1] + a2[2] + a2[3];
  float mean = s * (1.f / 768.f);
  float var = s2 * (1.f / 768.f) - mean * mean;
  float rstd = rsqrtf(var + 1e-5f);
  float* x2r = x2 + (size_t)row * D_;
  u16* orow = out + (size_t)row * D_;
  #pragma unroll
  for (int j = 0; j < 3; ++j) {
    int i = threadIdx.x + j * 256;
    x2r[i] = vv[j];
    orow[i] = f2bf((vv[j] - mean) * rstd * g[i] + b[i]);
  }
}

// ============ staged 128x128 GEMM core (m97 pattern), K-stride 32 ============
template <int K>
__device__ __forceinline__ void staged_core(const u16* __restrict__ Ab,
                                            const u16* __restrict__ Bb,
                                            u16* As, u16* Bs, f4 acc[4][4]) {
  const int wave = threadIdx.x >> 6, lane = threadIdx.x & 63;
  const int l15 = lane & 15, quad = lane >> 4;
  const int lrow = lane >> 2;
  const int lcol = (lane & 3) * 8;
  const int mw = (wave & 1) * 64, nw = (wave >> 1) * 64;
  for (int k0 = 0; k0 < K; k0 += 32) {
    const u16* ga = Ab + (size_t)(wave * 32 + lrow) * K + k0 + lcol;
    gl_lds16(ga, &As[(wave * 32) * 32]);
    gl_lds16(ga + (size_t)16 * K, &As[(wave * 32 + 16) * 32]);
    const u16* gb = Bb + (size_t)(wave * 32 + lrow) * K + k0 + lcol;
    gl_lds16(gb, &Bs[(wave * 32) * 32]);
    gl_lds16(gb + (size_t)16 * K, &Bs[(wave * 32 + 16) * 32]);
    __syncthreads();
    bf8 a[4], b[4];
    #pragma unroll
    for (int mt = 0; mt < 4; ++mt)
      a[mt] = *reinterpret_cast<const bf8*>(&As[(mw + mt * 16 + l15) * 32 + quad * 8]);
    #pragma unroll
    for (int nt = 0; nt < 4; ++nt)
      b[nt] = *reinterpret_cast<const bf8*>(&Bs[(nw + nt * 16 + l15) * 32 + quad * 8]);
    #pragma unroll
    for (int mt = 0; mt < 4; ++mt)
      #pragma unroll
      for (int nt = 0; nt < 4; ++nt)
        acc[mt][nt] = mfma16(a[mt], b[nt], acc[mt][nt]);
    __syncthreads();
  }
}

// ---------------- QKV GEMM staged ----------------
__global__ __launch_bounds__(256) void gemm_qkv_k(const u16* __restrict__ hln,
                                                  const u16* __restrict__ wT,
                                                  const float* __restrict__ bias,
                                                  u16* __restrict__ Q, u16* __restrict__ Km,
                                                  u16* __restrict__ Vt) {
  __shared__ u16 As[128 * 32], Bs[128 * 32];
  int m0 = blockIdx.y * 128, n0 = blockIdx.x * 128;
  f4 acc[4][4];
  ZERO44(acc);
  staged_core<768>(hln + (size_t)m0 * 768, wT + (size_t)n0 * 768, As, Bs, acc);
  int wave = threadIdx.x >> 6, lane = threadIdx.x & 63, l15 = lane & 15, quad = lane >> 4;
  int mW = m0 + (wave & 1) * 64, nW = n0 + (wave >> 1) * 64;
  #pragma unroll
  for (int mt = 0; mt < 4; ++mt)
    #pragma unroll
    for (int nt = 0; nt < 4; ++nt)
      #pragma unroll
      for (int r = 0; r < 4; ++r) {
        int m = mW + mt * 16 + quad * 4 + r;
        int n = nW + nt * 16 + l15;
        float v = acc[mt][nt][r] + bias[n];
        u16 bv = f2bf(v);
        int b = m >> 11, p = m & 2047;
        int which = n / 768, hn = n % 768;
        int h = hn >> 6, d = hn & 63;
        if (which == 0)
          Q[((size_t)(b * H_ + h) * P_ + p) * HD_ + d] = bv;
        else if (which == 1)
          Km[((size_t)(b * H_ + h) * P_ + p) * HD_ + d] = bv;
        else
          Vt[((size_t)(b * H_ + h) * HD_ + d) * P_ + p] = bv;
      }
}

// ---------------- FC1 GEMM staged + exact GELU ----------------
__global__ __launch_bounds__(256) void gemm_fc1_k(const u16* __restrict__ A,
                                                  const u16* __restrict__ wT,
                                                  const float* __restrict__ bias,
                                                  u16* __restrict__ out) {
  __shared__ u16 As[128 * 32], Bs[128 * 32];
  int m0 = blockIdx.y * 128, n0 = blockIdx.x * 128;
  f4 acc[4][4];
  ZERO44(acc);
  staged_core<768>(A + (size_t)m0 * 768, wT + (size_t)n0 * 768, As, Bs, acc);
  int wave = threadIdx.x >> 6, lane = threadIdx.x & 63, l15 = lane & 15, quad = lane >> 4;
  int mW = m0 + (wave & 1) * 64, nW = n0 + (wave >> 1) * 64;
  #pragma unroll
  for (int mt = 0; mt < 4; ++mt)
    #pragma unroll
    for (int nt = 0; nt < 4; ++nt)
      #pragma unroll
      for (int r = 0; r < 4; ++r) {
        int m = mW + mt * 16 + quad * 4 + r;
        int n = nW + nt * 16 + l15;
        float v = acc[mt][nt][r] + bias[n];
        v = 0.5f * v * (1.f + erff(v * 0.70710678f));
        out[(size_t)m * 3072 + n] = f2bf(v);
      }
}

// ---------------- FC2 GEMM staged (BM=128, BN=64), +bias +residual -> fp32 ----------------
__global__ __launch_bounds__(256) void gemm_fc2_k(const u16* __restrict__ A,
                                                  const u16* __restrict__ wT,
                                                  const float* __restrict__ bias,
                                                  const float* __restrict__ resid,
                                                  float* __restrict__ out) {
  __shared__ u16 As[128 * 32], Bs[64 * 32];
  int wave = threadIdx.x >> 6, lane = threadIdx.x & 63, l15 = lane & 15, quad = lane >> 4;
  int lrow = lane >> 2, lcol = (lane & 3) * 8;
  int m0 = blockIdx.y * 128, n0 = blockIdx.x * 64;
  const u16* Ab = A + (size_t)m0 * 3072;
  const u16* Bb = wT + (size_t)n0 * 3072;
  int mw = (wave & 1) * 64, nw = (wave >> 1) * 32;
  f4 acc[4][2];
  #pragma unroll
  for (int i = 0; i < 4; ++i)
    #pragma unroll
    for (int j = 0; j < 2; ++j) acc[i][j] = f4{0.f, 0.f, 0.f, 0.f};
  for (int k0 = 0; k0 < 3072; k0 += 32) {
    const u16* ga = Ab + (size_t)(wave * 32 + lrow) * 3072 + k0 + lcol;
    gl_lds16(ga, &As[(wave * 32) * 32]);
    gl_lds16(ga + (size_t)16 * 3072, &As[(wave * 32 + 16) * 32]);
    const u16* gb = Bb + (size_t)(wave * 16 + lrow) * 3072 + k0 + lcol;
    gl_lds16(gb, &Bs[(wave * 16) * 32]);
    __syncthreads();
    bf8 a[4], b[2];
    #pragma unroll
    for (int mt = 0; mt < 4; ++mt)
      a[mt] = *reinterpret_cast<const bf8*>(&As[(mw + mt * 16 + l15) * 32 + quad * 8]);
    #pragma unroll
    for (int nt = 0; nt < 2; ++nt)
      b[nt] = *reinterpret_cast<const bf8*>(&Bs[(nw + nt * 16 + l15) * 32 + quad * 8]);
    #pragma unroll
    for (int mt = 0; mt < 4; ++mt)
      #pragma unroll
      for (int nt = 0; nt < 2; ++nt)
        acc[mt][nt] = mfma16(a[mt], b[nt], acc[mt][nt]);
    __syncthreads();
  }
  int mW = m0 + mw, nW = n0 + nw;
  #pragma unroll
  for (int mt = 0; mt < 4; ++mt)
    #pragma unroll
    for (int nt = 0; nt < 2; ++nt)
      #pragma unroll
      for (int r = 0; r < 4; ++r) {
        int m = mW + mt * 16 + quad * 4 + r;
        int n = nW + nt * 16 + l15;
        size_t idx = (size_t)m * 768 + n;
        out[idx] = acc[mt][nt][r] + bias[n] + resid[idx];
      }
}

// ======== fused attention v6: v5 pipeline, unspilled ========
// __launch_bounds__(768,3): 3 waves/EU = exactly 1 block/CU -> VGPR cap 170
// (default let the compiler target 2 blocks/CU -> 85-reg cap -> the pipeline
// state spilled to scratch; v5's WRITE_SIZE 43008 vs 24576 was the smoking gun).
// Per q-tile t (2 barriers, both phases carry work):
//   b1; [ V(t) loads issued; S(t+1)->ereg (reg-only, prefetched K(t+1));
//         R(t) by waves 0-7 ]
//   b2; [ PV(t): read E(t)[own]+R(t), MFMA; then write E(t+1); issue K(t+2) ]
// E(t+1) written only after PV(t)'s E-reads (same wave, program order).
// R stride 36 floats (144 B): f4 reads at inherent-minimum 8-way.
__global__ __launch_bounds__(768, 3) void attn_fused_k(const u16* __restrict__ Q,
                                                       const u16* __restrict__ Km,
                                                       const u16* __restrict__ Vt,
                                                       u16* __restrict__ O0,
                                                       u16* __restrict__ O1) {
  int id = blockIdx.x;
  int g = id & 7, pt = id >> 3;  // pt 0..31, 64 p-rows
  int b = g >> 1, qs = g & 1;
  int w = threadIdx.x >> 6, lane = threadIdx.x & 63, l15 = lane & 15, quad = lane >> 4;
  __shared__ __align__(16) u16 E[12][64][36];  // 55296 B, row stride 72 B
  __shared__ __align__(16) float R[64][36];    // 9216 B, row stride 144 B

  const u16* Qp = Q + ((size_t)(b * H_ + w) * P_ + pt * 64) * HD_;
  const u16* Kbase = Km + ((size_t)(b * H_ + w) * P_ + qs * 1024) * HD_;
  const u16* Vbase = Vt + (size_t)(b * H_ + w) * HD_ * P_ + qs * 1024;

  bf8 qf[4][2];
  #pragma unroll
  for (int nt = 0; nt < 4; ++nt)
    #pragma unroll
    for (int ks = 0; ks < 2; ++ks)
      qf[nt][ks] = *reinterpret_cast<const bf8*>(Qp + (size_t)(nt * 16 + l15) * HD_ + ks * 32 + quad * 8);

  f4 oacc[4][4];
  ZERO44(oacc);

  bf8 kf[2][2];  // single-buffered K fragments (loaded 1 tile ahead)

#define LOADK(t)                                                                      \
  {                                                                                   \
    const u16* Kp_ = Kbase + (size_t)(t) * 32 * HD_;                                  \
    _Pragma("unroll")                                                                 \
    for (int mt_ = 0; mt_ < 2; ++mt_)                                                 \
      _Pragma("unroll")                                                               \
      for (int ks_ = 0; ks_ < 2; ++ks_)                                               \
        kf[mt_][ks_] = *reinterpret_cast<const bf8*>(                                 \
            Kp_ + (size_t)(mt_ * 16 + l15) * HD_ + ks_ * 32 + quad * 8);              \
  }

#define SPHASE(ereg)                                                                  \
  {                                                                                   \
    _Pragma("unroll")                                                                 \
    for (int mt_ = 0; mt_ < 2; ++mt_) {                                               \
      f4 s_[4];                                                                       \
      _Pragma("unroll")                                                               \
      for (int nt_ = 0; nt_ < 4; ++nt_) s_[nt_] = f4{0.f, 0.f, 0.f, 0.f};             \
      _Pragma("unroll")                                                               \
      for (int nt_ = 0; nt_ < 4; ++nt_) {                                             \
        s_[nt_] = mfma16(kf[mt_][0], qf[nt_][0], s_[nt_]);                            \
        s_[nt_] = mfma16(kf[mt_][1], qf[nt_][1], s_[nt_]);                            \
      }                                                                               \
      _Pragma("unroll")                                                               \
      for (int nt_ = 0; nt_ < 4; ++nt_) {                                             \
        f4 e_;                                                                        \
        _Pragma("unroll")                                                             \
        for (int r_ = 0; r_ < 4; ++r_) e_[r_] = __builtin_amdgcn_exp2f(s_[nt_][r_] * EXPC_); \
        ereg[mt_][nt_] = pack4(e_);                                                   \
      }                                                                               \
    }                                                                                 \
  }

#define WRITEE(ereg)                                                                  \
  {                                                                                   \
    _Pragma("unroll")                                                                 \
    for (int mt_ = 0; mt_ < 2; ++mt_)                                                 \
      _Pragma("unroll")                                                               \
      for (int nt_ = 0; nt_ < 4; ++nt_)                                               \
        *reinterpret_cast<uint2*>(&E[w][nt_ * 16 + l15][mt_ * 16 + quad * 4]) =       \
            ereg[mt_][nt_];                                                           \
  }

  // prologue: S(0) -> E(0); prefetch K(1)
  LOADK(0);
  {
    uint2 er[2][4];
    SPHASE(er);
    WRITEE(er);
  }
  LOADK(1);

  for (int qt = 0; qt < 32; ++qt) {
    __syncthreads();  // b1: E(qt) visible to all
    bf8 vf[4];  // V(qt) issued now, consumed after b2
    #pragma unroll
    for (int dt = 0; dt < 4; ++dt)
      vf[dt] = *reinterpret_cast<const bf8*>(Vbase + (size_t)(dt * 16 + l15) * P_ + qt * 32 + quad * 8);
    uint2 ereg[2][4];
    if (qt < 31) SPHASE(ereg);  // S(qt+1) in registers, overlaps R(qt)
    if (threadIdx.x < 512) {
      int p = threadIdx.x >> 3, qc = (threadIdx.x & 7) * 4;
      f4 sum = {0.f, 0.f, 0.f, 0.f};
      #pragma unroll
      for (int h = 0; h < 12; ++h)
        sum += unpack4(*reinterpret_cast<const ushort4*>(&E[h][p][qc]));
      f4 rc;
      #pragma unroll
      for (int c = 0; c < 4; ++c) rc[c] = __builtin_amdgcn_rcpf(sum[c]);
      *reinterpret_cast<f4*>(&R[p][qc]) = rc;
    }
    __syncthreads();  // b2: R(qt) ready
    #pragma unroll
    for (int pi = 0; pi < 4; ++pi) {
      int pp = pi * 16 + l15;
      uint2 e0 = *reinterpret_cast<const uint2*>(&E[w][pp][quad * 8]);
      uint2 e1 = *reinterpret_cast<const uint2*>(&E[w][pp][quad * 8 + 4]);
      f4 r0 = *reinterpret_cast<const f4*>(&R[pp][quad * 8]);
      f4 r1 = *reinterpret_cast<const f4*>(&R[pp][quad * 8 + 4]);
      bf8 af = mkbf8(unp2(e0) * r0, unp2(e1) * r1);
      #pragma unroll
      for (int dt = 0; dt < 4; ++dt)
        oacc[dt][pi] = mfma16(vf[dt], af, oacc[dt][pi]);
    }
    if (qt < 31) {
      WRITEE(ereg);                 // E(qt+1), after this wave's E(qt) reads
      if (qt < 30) LOADK(qt + 2);   // prefetch, hidden under next S/R phase
    }
  }
  __syncthreads();
  // epilogue: stage O^T (bf16) through LDS (alias E as [6][64][72]) in 2 head-phases
  u16(*Os)[64][72] = reinterpret_cast<u16(*)[64][72]>(&E[0][0][0]);
  u16* Op = qs ? O1 : O0;
  #pragma unroll
  for (int hh = 0; hh < 2; ++hh) {
    if (w >= hh * 6 && w < hh * 6 + 6) {
      int wp = w - hh * 6;
      #pragma unroll
      for (int dt = 0; dt < 4; ++dt)
        #pragma unroll
        for (int pi = 0; pi < 4; ++pi)
          *reinterpret_cast<uint2*>(&Os[wp][pi * 16 + l15][dt * 16 + quad * 4]) = pack4(oacc[dt][pi]);
    }
    __syncthreads();
    #pragma unroll
    for (int j = 0; j < 4; ++j) {
      int c = threadIdx.x + j * 768;   // 0..3071
      int p = c / 48, m = c % 48;
      int hp = m >> 3, d = (m & 7) * 8;
      uint4 val = *reinterpret_cast<const uint4*>(&Os[hp][p][d]);
      size_t go = (((size_t)b * P_) + pt * 64 + p) * D_ + (hh * 6 + hp) * 64 + d;
      *reinterpret_cast<uint4*>(Op + go) = val;
    }
    __syncthreads();
  }
#undef LOADK
#undef SPHASE
#undef WRITEE
}

extern "C" void kernel_launch(void* const* d_in, const int* in_sizes, int n_in,
                              void* d_out, int out_size, void* d_ws, size_t ws_size,
                              hipStream_t stream) {
  const float* x = (const float*)d_in[0];
  const float* ln1w = (const float*)d_in[1];
  const float* ln1b = (const float*)d_in[2];
  const float* wqkv = (const float*)d_in[3];
  const float* bqkv = (const float*)d_in[4];
  const float* ln2w = (const float*)d_in[5];
  const float* ln2b = (const float*)d_in[6];
  const float* wfc1 = (const float*)d_in[7];
  const float* bfc1 = (const float*)d_in[8];
  const float* wfc2 = (const float*)d_in[9];
  const float* bfc2 = (const float*)d_in[10];
  float* out = (float*)d_out;

  char* ws = (char*)d_ws;
  size_t off = 0;
  auto alloc = [&](size_t bytes) -> void* {
    void* p = ws + off;
    off += (bytes + 255) & ~(size_t)255;
    return p;
  };
  u16* hln = (u16*)alloc((size_t)8192 * 768 * 2);
  u16* wqkvT = (u16*)alloc((size_t)2304 * 768 * 2);
  u16* wfc1T = (u16*)alloc((size_t)3072 * 768 * 2);
  u16* wfc2T = (u16*)alloc((size_t)768 * 3072 * 2);
  u16* Qb = (u16*)alloc((size_t)B_ * H_ * P_ * HD_ * 2);
  u16* Kb = (u16*)alloc((size_t)B_ * H_ * P_ * HD_ * 2);
  u16* Vtb = (u16*)alloc((size_t)B_ * H_ * HD_ * P_ * 2);
  float* x2 = (float*)alloc((size_t)8192 * 768 * 4);
  u16* O0 = (u16*)alloc((size_t)8192 * 768 * 2);
  u16* O1 = (u16*)alloc((size_t)8192 * 768 * 2);
  u16* gbuf = (u16*)alloc((size_t)8192 * 3072 * 2);

  tcast_k<<<dim3(72, 24), 256, 0, stream>>>(wqkv, wqkvT, 768, 2304);
  tcast_k<<<dim3(96, 24), 256, 0, stream>>>(wfc1, wfc1T, 768, 3072);
  tcast_k<<<dim3(24, 96), 256, 0, stream>>>(wfc2, wfc2T, 3072, 768);
  ln_k<<<8192, 256, 0, stream>>>(x, ln1w, ln1b, hln);
  gemm_qkv_k<<<dim3(18, 64), 256, 0, stream>>>(hln, wqkvT, bqkv, Qb, Kb, Vtb);
  attn_fused_k<<<256, 768, 0, stream>>>(Qb, Kb, Vtb, O0, O1);
  ln2add_k<<<8192, 256, 0, stream>>>(x, O0, O1, ln2w, ln2b, x2, hln);
  gemm_fc1_k<<<dim3(24, 64), 256, 0, stream>>>(hln, wfc1T, bfc1, gbuf);
  gemm_fc2_k<<<dim3(12, 64), 256, 0, stream>>>(gbuf, wfc2T, bfc2, x2, out);
}

// Round 5
// 480.336 us; speedup vs baseline: 1.0725x; 1.0725x over previous
//
#include <hip/hip_runtime.h>
#include <hip/hip_bf16.h>

typedef __bf16 bf8 __attribute__((ext_vector_type(8)));
typedef float f4 __attribute__((ext_vector_type(4)));
typedef unsigned short u16;
typedef unsigned int u32;

#define B_ 4
#define P_ 2048
#define D_ 768
#define H_ 12
#define HD_ 64
// scale * log2(e): exp(s*0.125) = exp2(s * 0.18033688)
#define EXPC_ 0.18033688011112042f

typedef const __attribute__((address_space(1))) void gvoid;
typedef __attribute__((address_space(3))) void lvoid;

__device__ __forceinline__ void gl_lds16(const u16* g, u16* l) {
  __builtin_amdgcn_global_load_lds((gvoid*)g, (lvoid*)l, 16, 0, 0);
}

__device__ __forceinline__ u16 f2bf(float f) {  // RNE
  union { float f; u32 u; } c; c.f = f;
  u32 u = c.u;
  u += 0x7fffu + ((u >> 16) & 1u);
  return (u16)(u >> 16);
}

__device__ __forceinline__ float bf2f(u16 v) {
  union { u32 u; float f; } c; c.u = (u32)v << 16; return c.f;
}

__device__ __forceinline__ uint2 pack4(f4 v) {  // truncating 4xf32 -> 4xbf16
  union { float f; u32 u; } a, b, c, d;
  a.f = v[0]; b.f = v[1]; c.f = v[2]; d.f = v[3];
  uint2 r;
  r.x = (a.u >> 16) | (b.u & 0xffff0000u);
  r.y = (c.u >> 16) | (d.u & 0xffff0000u);
  return r;
}

__device__ __forceinline__ f4 unpack4(ushort4 v) {
  f4 r;
  r[0] = bf2f(v.x); r[1] = bf2f(v.y); r[2] = bf2f(v.z); r[3] = bf2f(v.w);
  return r;
}

__device__ __forceinline__ f4 unp2(uint2 u) {
  f4 r;
  r[0] = bf2f((u16)(u.x & 0xffffu)); r[1] = bf2f((u16)(u.x >> 16));
  r[2] = bf2f((u16)(u.y & 0xffffu)); r[3] = bf2f((u16)(u.y >> 16));
  return r;
}

__device__ __forceinline__ bf8 mkbf8(f4 a, f4 b) {
  union { uint4 u; bf8 v; } c;
  uint2 l = pack4(a), h = pack4(b);
  c.u = make_uint4(l.x, l.y, h.x, h.y);
  return c.v;
}

__device__ __forceinline__ f4 mfma16(bf8 a, bf8 b, f4 c) {
  return __builtin_amdgcn_mfma_f32_16x16x32_bf16(a, b, c, 0, 0, 0);
}

#define ZERO44(acc)                    \
  {                                    \
    f4 z_ = {0.f, 0.f, 0.f, 0.f};      \
    for (int i_ = 0; i_ < 4; ++i_)     \
      for (int j_ = 0; j_ < 4; ++j_)   \
        acc[i_][j_] = z_;              \
  }

// XCD-bijective swizzle for grids with nwg % 8 == 0 (m157): each XCD gets a
// contiguous chunk of row-major tiles -> B-panel L2 reuse within XCD.
__device__ __forceinline__ int xcd_swz(int lin, int nwg) {
  return (lin & 7) * (nwg >> 3) + (lin >> 3);
}

// ---------------- transpose-cast fp32 (R,C) -> bf16 (C,R) ----------------
__global__ __launch_bounds__(256) void tcast_k(const float* __restrict__ src,
                                               u16* __restrict__ dst, int R, int C) {
  __shared__ float t[32][33];
  int c0 = blockIdx.x * 32, r0 = blockIdx.y * 32;
  int tx = threadIdx.x & 31, ty = threadIdx.x >> 5;
  #pragma unroll
  for (int i = 0; i < 32; i += 8) {
    int r = r0 + ty + i, c = c0 + tx;
    t[ty + i][tx] = (r < R && c < C) ? src[(size_t)r * C + c] : 0.f;
  }
  __syncthreads();
  #pragma unroll
  for (int i = 0; i < 32; i += 8) {
    int c = c0 + ty + i, r = r0 + tx;
    if (c < C && r < R) dst[(size_t)c * R + r] = f2bf(t[tx][ty + i]);
  }
}

// ---------------- layernorm fp32 -> bf16 (LN1) ----------------
__global__ __launch_bounds__(256) void ln_k(const float* __restrict__ x,
                                            const float* __restrict__ g,
                                            const float* __restrict__ b,
                                            u16* __restrict__ out) {
  int row = blockIdx.x;
  const float* xr = x + (size_t)row * D_;
  float v0 = xr[threadIdx.x], v1 = xr[threadIdx.x + 256], v2 = xr[threadIdx.x + 512];
  float s = v0 + v1 + v2;
  float s2 = v0 * v0 + v1 * v1 + v2 * v2;
  #pragma unroll
  for (int o = 32; o > 0; o >>= 1) {
    s += __shfl_down(s, o, 64);
    s2 += __shfl_down(s2, o, 64);
  }
  __shared__ float a[4], a2[4];
  int wv = threadIdx.x >> 6;
  if ((threadIdx.x & 63) == 0) { a[wv] = s; a2[wv] = s2; }
  __syncthreads();
  s = a[0] + a[1] + a[2] + a[3];
  s2 = a2[0] + a2[1] + a2[2] + a2[3];
  float mean = s * (1.f / 768.f);
  float var = s2 * (1.f / 768.f) - mean * mean;
  float rstd = rsqrtf(var + 1e-5f);
  u16* orow = out + (size_t)row * D_;
  float vv[3] = {v0, v1, v2};
  #pragma unroll
  for (int j = 0; j < 3; ++j) {
    int i = threadIdx.x + j * 256;
    orow[i] = f2bf((vv[j] - mean) * rstd * g[i] + b[i]);
  }
}

// ---------------- x2 = x + O0 + O1; hln = LN(x2) (LN2 fused with partial-O sum) ----------------
__global__ __launch_bounds__(256) void ln2add_k(const float* __restrict__ x,
                                                const u16* __restrict__ O0,
                                                const u16* __restrict__ O1,
                                                const float* __restrict__ g,
                                                const float* __restrict__ b,
                                                float* __restrict__ x2,
                                                u16* __restrict__ out) {
  int row = blockIdx.x;
  const float* xr = x + (size_t)row * D_;
  const u16* o0 = O0 + (size_t)row * D_;
  const u16* o1 = O1 + (size_t)row * D_;
  float vv[3];
  #pragma unroll
  for (int j = 0; j < 3; ++j) {
    int i = threadIdx.x + j * 256;
    vv[j] = xr[i] + bf2f(o0[i]) + bf2f(o1[i]);
  }
  float s = vv[0] + vv[1] + vv[2];
  float s2 = vv[0] * vv[0] + vv[1] * vv[1] + vv[2] * vv[2];
  #pragma unroll
  for (int o = 32; o > 0; o >>= 1) {
    s += __shfl_down(s, o, 64);
    s2 += __shfl_down(s2, o, 64);
  }
  __shared__ float a[4], a2[4];
  int wv = threadIdx.x >> 6;
  if ((threadIdx.x & 63) == 0) { a[wv] = s; a2[wv] = s2; }
  __syncthreads();
  s = a[0] + a[1] + a[2] + a[3];
  s2 = a2[0] + a2[1] + a2[2] + a2[3];
  float mean = s * (1.f / 768.f);
  float var = s2 * (1.f / 768.f) - mean * mean;
  float rstd = rsqrtf(var + 1e-5f);
  float* x2r = x2 + (size_t)row * D_;
  u16* orow = out + (size_t)row * D_;
  #pragma unroll
  for (int j = 0; j < 3; ++j) {
    int i = threadIdx.x + j * 256;
    x2r[i] = vv[j];
    orow[i] = f2bf((vv[j] - mean) * rstd * g[i] + b[i]);
  }
}

// ============ staged 128x128 GEMM core (m97 pattern), K-stride 32 ============
template <int K>
__device__ __forceinline__ void staged_core(const u16* __restrict__ Ab,
                                            const u16* __restrict__ Bb,
                                            u16* As, u16* Bs, f4 acc[4][4]) {
  const int wave = threadIdx.x >> 6, lane = threadIdx.x & 63;
  const int l15 = lane & 15, quad = lane >> 4;
  const int lrow = lane >> 2;
  const int lcol = (lane & 3) * 8;
  const int mw = (wave & 1) * 64, nw = (wave >> 1) * 64;
  for (int k0 = 0; k0 < K; k0 += 32) {
    const u16* ga = Ab + (size_t)(wave * 32 + lrow) * K + k0 + lcol;
    gl_lds16(ga, &As[(wave * 32) * 32]);
    gl_lds16(ga + (size_t)16 * K, &As[(wave * 32 + 16) * 32]);
    const u16* gb = Bb + (size_t)(wave * 32 + lrow) * K + k0 + lcol;
    gl_lds16(gb, &Bs[(wave * 32) * 32]);
    gl_lds16(gb + (size_t)16 * K, &Bs[(wave * 32 + 16) * 32]);
    __syncthreads();
    bf8 a[4], b[4];
    #pragma unroll
    for (int mt = 0; mt < 4; ++mt)
      a[mt] = *reinterpret_cast<const bf8*>(&As[(mw + mt * 16 + l15) * 32 + quad * 8]);
    #pragma unroll
    for (int nt = 0; nt < 4; ++nt)
      b[nt] = *reinterpret_cast<const bf8*>(&Bs[(nw + nt * 16 + l15) * 32 + quad * 8]);
    __builtin_amdgcn_s_setprio(1);
    #pragma unroll
    for (int mt = 0; mt < 4; ++mt)
      #pragma unroll
      for (int nt = 0; nt < 4; ++nt)
        acc[mt][nt] = mfma16(a[mt], b[nt], acc[mt][nt]);
    __builtin_amdgcn_s_setprio(0);
    __syncthreads();
  }
}

// ---------------- QKV GEMM staged ----------------
__global__ __launch_bounds__(256) void gemm_qkv_k(const u16* __restrict__ hln,
                                                  const u16* __restrict__ wT,
                                                  const float* __restrict__ bias,
                                                  u16* __restrict__ Q, u16* __restrict__ Km,
                                                  u16* __restrict__ Vt) {
  __shared__ u16 As[128 * 32], Bs[128 * 32];
  int lin = blockIdx.y * gridDim.x + blockIdx.x;
  int swz = xcd_swz(lin, gridDim.x * gridDim.y);
  int m0 = (swz / gridDim.x) * 128, n0 = (swz % gridDim.x) * 128;
  f4 acc[4][4];
  ZERO44(acc);
  staged_core<768>(hln + (size_t)m0 * 768, wT + (size_t)n0 * 768, As, Bs, acc);
  int wave = threadIdx.x >> 6, lane = threadIdx.x & 63, l15 = lane & 15, quad = lane >> 4;
  int mW = m0 + (wave & 1) * 64, nW = n0 + (wave >> 1) * 64;
  #pragma unroll
  for (int mt = 0; mt < 4; ++mt)
    #pragma unroll
    for (int nt = 0; nt < 4; ++nt)
      #pragma unroll
      for (int r = 0; r < 4; ++r) {
        int m = mW + mt * 16 + quad * 4 + r;
        int n = nW + nt * 16 + l15;
        float v = acc[mt][nt][r] + bias[n];
        u16 bv = f2bf(v);
        int b = m >> 11, p = m & 2047;
        int which = n / 768, hn = n % 768;
        int h = hn >> 6, d = hn & 63;
        if (which == 0)
          Q[((size_t)(b * H_ + h) * P_ + p) * HD_ + d] = bv;
        else if (which == 1)
          Km[((size_t)(b * H_ + h) * P_ + p) * HD_ + d] = bv;
        else
          Vt[((size_t)(b * H_ + h) * HD_ + d) * P_ + p] = bv;
      }
}

// ---------------- FC1 GEMM staged + exact GELU ----------------
__global__ __launch_bounds__(256) void gemm_fc1_k(const u16* __restrict__ A,
                                                  const u16* __restrict__ wT,
                                                  const float* __restrict__ bias,
                                                  u16* __restrict__ out) {
  __shared__ u16 As[128 * 32], Bs[128 * 32];
  int lin = blockIdx.y * gridDim.x + blockIdx.x;
  int swz = xcd_swz(lin, gridDim.x * gridDim.y);
  int m0 = (swz / gridDim.x) * 128, n0 = (swz % gridDim.x) * 128;
  f4 acc[4][4];
  ZERO44(acc);
  staged_core<768>(A + (size_t)m0 * 768, wT + (size_t)n0 * 768, As, Bs, acc);
  int wave = threadIdx.x >> 6, lane = threadIdx.x & 63, l15 = lane & 15, quad = lane >> 4;
  int mW = m0 + (wave & 1) * 64, nW = n0 + (wave >> 1) * 64;
  #pragma unroll
  for (int mt = 0; mt < 4; ++mt)
    #pragma unroll
    for (int nt = 0; nt < 4; ++nt)
      #pragma unroll
      for (int r = 0; r < 4; ++r) {
        int m = mW + mt * 16 + quad * 4 + r;
        int n = nW + nt * 16 + l15;
        float v = acc[mt][nt][r] + bias[n];
        v = 0.5f * v * (1.f + erff(v * 0.70710678f));
        out[(size_t)m * 3072 + n] = f2bf(v);
      }
}

// ---------------- FC2 GEMM staged (BM=128, BN=64), +bias +residual -> fp32 ----------------
__global__ __launch_bounds__(256) void gemm_fc2_k(const u16* __restrict__ A,
                                                  const u16* __restrict__ wT,
                                                  const float* __restrict__ bias,
                                                  const float* __restrict__ resid,
                                                  float* __restrict__ out) {
  __shared__ u16 As[128 * 32], Bs[64 * 32];
  int wave = threadIdx.x >> 6, lane = threadIdx.x & 63, l15 = lane & 15, quad = lane >> 4;
  int lrow = lane >> 2, lcol = (lane & 3) * 8;
  int lin = blockIdx.y * gridDim.x + blockIdx.x;
  int swz = xcd_swz(lin, gridDim.x * gridDim.y);
  int m0 = (swz / gridDim.x) * 128, n0 = (swz % gridDim.x) * 64;
  const u16* Ab = A + (size_t)m0 * 3072;
  const u16* Bb = wT + (size_t)n0 * 3072;
  int mw = (wave & 1) * 64, nw = (wave >> 1) * 32;
  f4 acc[4][2];
  #pragma unroll
  for (int i = 0; i < 4; ++i)
    #pragma unroll
    for (int j = 0; j < 2; ++j) acc[i][j] = f4{0.f, 0.f, 0.f, 0.f};
  for (int k0 = 0; k0 < 3072; k0 += 32) {
    const u16* ga = Ab + (size_t)(wave * 32 + lrow) * 3072 + k0 + lcol;
    gl_lds16(ga, &As[(wave * 32) * 32]);
    gl_lds16(ga + (size_t)16 * 3072, &As[(wave * 32 + 16) * 32]);
    const u16* gb = Bb + (size_t)(wave * 16 + lrow) * 3072 + k0 + lcol;
    gl_lds16(gb, &Bs[(wave * 16) * 32]);
    __syncthreads();
    bf8 a[4], b[2];
    #pragma unroll
    for (int mt = 0; mt < 4; ++mt)
      a[mt] = *reinterpret_cast<const bf8*>(&As[(mw + mt * 16 + l15) * 32 + quad * 8]);
    #pragma unroll
    for (int nt = 0; nt < 2; ++nt)
      b[nt] = *reinterpret_cast<const bf8*>(&Bs[(nw + nt * 16 + l15) * 32 + quad * 8]);
    __builtin_amdgcn_s_setprio(1);
    #pragma unroll
    for (int mt = 0; mt < 4; ++mt)
      #pragma unroll
      for (int nt = 0; nt < 2; ++nt)
        acc[mt][nt] = mfma16(a[mt], b[nt], acc[mt][nt]);
    __builtin_amdgcn_s_setprio(0);
    __syncthreads();
  }
  int mW = m0 + mw, nW = n0 + nw;
  #pragma unroll
  for (int mt = 0; mt < 4; ++mt)
    #pragma unroll
    for (int nt = 0; nt < 2; ++nt)
      #pragma unroll
      for (int r = 0; r < 4; ++r) {
        int m = mW + mt * 16 + quad * 4 + r;
        int n = nW + nt * 16 + l15;
        size_t idx = (size_t)m * 768 + n;
        out[idx] = acc[mt][nt][r] + bias[n] + resid[idx];
      }
}

// ======== fused attention v7: v3 structure (proven spill-free) + R-pad + setprio ========
// Grid: 256 blocks, 1/CU. g=id&7 -> XCD; (b,qs)=g so each XCD streams ONE (b,qs)
// K/V sequence (L2-resident). 768 threads = 12 waves = 12 heads.
// Per 32-wide q-tile: wave w computes S^T (q32 x p64) for head w, exp -> E[w];
// 512 threads compute R[p][q] = 1/sum_h E; wave w rescales its own E[w] fragments
// in registers for the AV MFMA. 2 barriers per tile.
// R stride 36 floats (144 B): PV b128 R-read at inherent-minimum 8-way
// (was 16-way at stride 128 B -> half the conflict cycles).
__global__ __launch_bounds__(768) void attn_fused_k(const u16* __restrict__ Q,
                                                    const u16* __restrict__ Km,
                                                    const u16* __restrict__ Vt,
                                                    u16* __restrict__ O0,
                                                    u16* __restrict__ O1) {
  int id = blockIdx.x;
  int g = id & 7, pt = id >> 3;
  int b = g >> 1, qs = g & 1;
  int w = threadIdx.x >> 6, lane = threadIdx.x & 63, l15 = lane & 15, quad = lane >> 4;
  __shared__ __align__(16) u16 E[12][64][36];  // 55296 B, row stride 72 B
  __shared__ __align__(16) float R[64][36];    // 9216 B, row stride 144 B

  const u16* Qp = Q + ((size_t)(b * H_ + w) * P_ + pt * 64) * HD_;
  const u16* Kbase = Km + ((size_t)(b * H_ + w) * P_ + qs * 1024) * HD_;
  const u16* Vbase = Vt + (size_t)(b * H_ + w) * HD_ * P_ + qs * 1024;

  // Q fragments: 64 p-rows of this wave's head (persist across all q-tiles)
  bf8 qf[4][2];
  #pragma unroll
  for (int nt = 0; nt < 4; ++nt)
    #pragma unroll
    for (int ks = 0; ks < 2; ++ks)
      qf[nt][ks] = *reinterpret_cast<const bf8*>(Qp + (size_t)(nt * 16 + l15) * HD_ + ks * 32 + quad * 8);

  f4 oacc[4][4];  // O^T: d (4x16) x p (4x16)
  ZERO44(oacc);

  for (int qt = 0; qt < 32; ++qt) {
    const u16* Kp = Kbase + (size_t)qt * 32 * HD_;
    // K fragments for this 32-q tile
    bf8 kf[2][2];
    #pragma unroll
    for (int mt = 0; mt < 2; ++mt)
      #pragma unroll
      for (int ks = 0; ks < 2; ++ks)
        kf[mt][ks] = *reinterpret_cast<const bf8*>(Kp + (size_t)(mt * 16 + l15) * HD_ + ks * 32 + quad * 8);
    // V fragments issued early (drain during S/exp)
    bf8 vf[4];
    #pragma unroll
    for (int dt = 0; dt < 4; ++dt)
      vf[dt] = *reinterpret_cast<const bf8*>(Vbase + (size_t)(dt * 16 + l15) * P_ + qt * 32 + quad * 8);
    // S^T + exp -> E[w], one mt (16 q-rows) at a time
    #pragma unroll
    for (int mt = 0; mt < 2; ++mt) {
      f4 s[4];
      #pragma unroll
      for (int nt = 0; nt < 4; ++nt) s[nt] = f4{0.f, 0.f, 0.f, 0.f};
      __builtin_amdgcn_s_setprio(1);
      #pragma unroll
      for (int nt = 0; nt < 4; ++nt) {
        s[nt] = mfma16(kf[mt][0], qf[nt][0], s[nt]);
        s[nt] = mfma16(kf[mt][1], qf[nt][1], s[nt]);
      }
      __builtin_amdgcn_s_setprio(0);
      #pragma unroll
      for (int nt = 0; nt < 4; ++nt) {
        f4 e;
        #pragma unroll
        for (int r = 0; r < 4; ++r) e[r] = __builtin_amdgcn_exp2f(s[nt][r] * EXPC_);
        *reinterpret_cast<uint2*>(&E[w][nt * 16 + l15][mt * 16 + quad * 4]) = pack4(e);
      }
    }
    __syncthreads();
    // R[p][q] = 1 / sum_h E[h][p][q]  (512 threads, one f4 chunk each)
    if (threadIdx.x < 512) {
      int p = threadIdx.x >> 3, qc = (threadIdx.x & 7) * 4;
      f4 sum = {0.f, 0.f, 0.f, 0.f};
      #pragma unroll
      for (int h = 0; h < 12; ++h)
        sum += unpack4(*reinterpret_cast<const ushort4*>(&E[h][p][qc]));
      f4 rc;
      #pragma unroll
      for (int c = 0; c < 4; ++c) rc[c] = __builtin_amdgcn_rcpf(sum[c]);
      *reinterpret_cast<f4*>(&R[p][qc]) = rc;
    }
    __syncthreads();
    // O^T += V^T-frag @ (E[w]*R)-frag
    #pragma unroll
    for (int pi = 0; pi < 4; ++pi) {
      int pp = pi * 16 + l15;
      uint2 e0 = *reinterpret_cast<const uint2*>(&E[w][pp][quad * 8]);
      uint2 e1 = *reinterpret_cast<const uint2*>(&E[w][pp][quad * 8 + 4]);
      f4 r0 = *reinterpret_cast<const f4*>(&R[pp][quad * 8]);
      f4 r1 = *reinterpret_cast<const f4*>(&R[pp][quad * 8 + 4]);
      bf8 af = mkbf8(unp2(e0) * r0, unp2(e1) * r1);
      __builtin_amdgcn_s_setprio(1);
      #pragma unroll
      for (int dt = 0; dt < 4; ++dt)
        oacc[dt][pi] = mfma16(vf[dt], af, oacc[dt][pi]);
      __builtin_amdgcn_s_setprio(0);
    }
    // no trailing barrier: E[w] is written and read only by wave w; R guarded by b1/b2
  }
  __syncthreads();
  // epilogue: stage O^T (bf16) through LDS (alias E as [6][64][72]) in 2 head-phases
  u16(*Os)[64][72] = reinterpret_cast<u16(*)[64][72]>(&E[0][0][0]);
  u16* Op = qs ? O1 : O0;
  #pragma unroll
  for (int hh = 0; hh < 2; ++hh) {
    if (w >= hh * 6 && w < hh * 6 + 6) {
      int wp = w - hh * 6;
      #pragma unroll
      for (int dt = 0; dt < 4; ++dt)
        #pragma unroll
        for (int pi = 0; pi < 4; ++pi)
          *reinterpret_cast<uint2*>(&Os[wp][pi * 16 + l15][dt * 16 + quad * 4]) = pack4(oacc[dt][pi]);
    }
    __syncthreads();
    #pragma unroll
    for (int j = 0; j < 4; ++j) {
      int c = threadIdx.x + j * 768;   // 0..3071
      int p = c / 48, m = c % 48;
      int hp = m >> 3, d = (m & 7) * 8;
      uint4 val = *reinterpret_cast<const uint4*>(&Os[hp][p][d]);
      size_t go = (((size_t)b * P_) + pt * 64 + p) * D_ + (hh * 6 + hp) * 64 + d;
      *reinterpret_cast<uint4*>(Op + go) = val;
    }
    __syncthreads();
  }
}

extern "C" void kernel_launch(void* const* d_in, const int* in_sizes, int n_in,
                              void* d_out, int out_size, void* d_ws, size_t ws_size,
                              hipStream_t stream) {
  const float* x = (const float*)d_in[0];
  const float* ln1w = (const float*)d_in[1];
  const float* ln1b = (const float*)d_in[2];
  const float* wqkv = (const float*)d_in[3];
  const float* bqkv = (const float*)d_in[4];
  const float* ln2w = (const float*)d_in[5];
  const float* ln2b = (const float*)d_in[6];
  const float* wfc1 = (const float*)d_in[7];
  const float* bfc1 = (const float*)d_in[8];
  const float* wfc2 = (const float*)d_in[9];
  const float* bfc2 = (const float*)d_in[10];
  float* out = (float*)d_out;

  char* ws = (char*)d_ws;
  size_t off = 0;
  auto alloc = [&](size_t bytes) -> void* {
    void* p = ws + off;
    off += (bytes + 255) & ~(size_t)255;
    return p;
  };
  u16* hln = (u16*)alloc((size_t)8192 * 768 * 2);
  u16* wqkvT = (u16*)alloc((size_t)2304 * 768 * 2);
  u16* wfc1T = (u16*)alloc((size_t)3072 * 768 * 2);
  u16* wfc2T = (u16*)alloc((size_t)768 * 3072 * 2);
  u16* Qb = (u16*)alloc((size_t)B_ * H_ * P_ * HD_ * 2);
  u16* Kb = (u16*)alloc((size_t)B_ * H_ * P_ * HD_ * 2);
  u16* Vtb = (u16*)alloc((size_t)B_ * H_ * HD_ * P_ * 2);
  float* x2 = (float*)alloc((size_t)8192 * 768 * 4);
  u16* O0 = (u16*)alloc((size_t)8192 * 768 * 2);
  u16* O1 = (u16*)alloc((size_t)8192 * 768 * 2);
  u16* gbuf = (u16*)alloc((size_t)8192 * 3072 * 2);

  tcast_k<<<dim3(72, 24), 256, 0, stream>>>(wqkv, wqkvT, 768, 2304);
  tcast_k<<<dim3(96, 24), 256, 0, stream>>>(wfc1, wfc1T, 768, 3072);
  tcast_k<<<dim3(24, 96), 256, 0, stream>>>(wfc2, wfc2T, 3072, 768);
  ln_k<<<8192, 256, 0, stream>>>(x, ln1w, ln1b, hln);
  gemm_qkv_k<<<dim3(18, 64), 256, 0, stream>>>(hln, wqkvT, bqkv, Qb, Kb, Vtb);
  attn_fused_k<<<256, 768, 0, stream>>>(Qb, Kb, Vtb, O0, O1);
  ln2add_k<<<8192, 256, 0, stream>>>(x, O0, O1, ln2w, ln2b, x2, hln);
  gemm_fc1_k<<<dim3(24, 64), 256, 0, stream>>>(hln, wfc1T, bfc1, gbuf);
  gemm_fc2_k<<<dim3(12, 64), 256, 0, stream>>>(gbuf, wfc2T, bfc2, x2, out);
}

// Round 6
// 479.501 us; speedup vs baseline: 1.0744x; 1.0017x over previous
//
#include <hip/hip_runtime.h>
#include <hip/hip_bf16.h>

typedef __bf16 bf8 __attribute__((ext_vector_type(8)));
typedef float f4 __attribute__((ext_vector_type(4)));
typedef unsigned short u16;
typedef unsigned int u32;

#define B_ 4
#define P_ 2048
#define D_ 768
#define H_ 12
#define HD_ 64
// scale * log2(e): exp(s*0.125) = exp2(s * 0.18033688)
#define EXPC_ 0.18033688011112042f

typedef const __attribute__((address_space(1))) void gvoid;
typedef __attribute__((address_space(3))) void lvoid;

__device__ __forceinline__ void gl_lds16(const u16* g, u16* l) {
  __builtin_amdgcn_global_load_lds((gvoid*)g, (lvoid*)l, 16, 0, 0);
}

__device__ __forceinline__ u16 f2bf(float f) {  // RNE
  union { float f; u32 u; } c; c.f = f;
  u32 u = c.u;
  u += 0x7fffu + ((u >> 16) & 1u);
  return (u16)(u >> 16);
}

__device__ __forceinline__ float bf2f(u16 v) {
  union { u32 u; float f; } c; c.u = (u32)v << 16; return c.f;
}

__device__ __forceinline__ uint2 pack4(f4 v) {  // truncating 4xf32 -> 4xbf16
  union { float f; u32 u; } a, b, c, d;
  a.f = v[0]; b.f = v[1]; c.f = v[2]; d.f = v[3];
  uint2 r;
  r.x = (a.u >> 16) | (b.u & 0xffff0000u);
  r.y = (c.u >> 16) | (d.u & 0xffff0000u);
  return r;
}

__device__ __forceinline__ f4 unpack4(ushort4 v) {
  f4 r;
  r[0] = bf2f(v.x); r[1] = bf2f(v.y); r[2] = bf2f(v.z); r[3] = bf2f(v.w);
  return r;
}

__device__ __forceinline__ f4 unp2(uint2 u) {
  f4 r;
  r[0] = bf2f((u16)(u.x & 0xffffu)); r[1] = bf2f((u16)(u.x >> 16));
  r[2] = bf2f((u16)(u.y & 0xffffu)); r[3] = bf2f((u16)(u.y >> 16));
  return r;
}

__device__ __forceinline__ bf8 mkbf8(f4 a, f4 b) {
  union { uint4 u; bf8 v; } c;
  uint2 l = pack4(a), h = pack4(b);
  c.u = make_uint4(l.x, l.y, h.x, h.y);
  return c.v;
}

__device__ __forceinline__ f4 mfma16(bf8 a, bf8 b, f4 c) {
  return __builtin_amdgcn_mfma_f32_16x16x32_bf16(a, b, c, 0, 0, 0);
}

#define ZERO44(acc)                    \
  {                                    \
    f4 z_ = {0.f, 0.f, 0.f, 0.f};      \
    for (int i_ = 0; i_ < 4; ++i_)     \
      for (int j_ = 0; j_ < 4; ++j_)   \
        acc[i_][j_] = z_;              \
  }

// XCD-bijective swizzle for grids with nwg % 8 == 0 (m157): each XCD gets a
// contiguous chunk of row-major tiles -> B-panel L2 reuse within XCD.
__device__ __forceinline__ int xcd_swz(int lin, int nwg) {
  return (lin & 7) * (nwg >> 3) + (lin >> 3);
}

// ---------------- transpose-cast fp32 (R,C) -> bf16 (C,R) ----------------
__global__ __launch_bounds__(256) void tcast_k(const float* __restrict__ src,
                                               u16* __restrict__ dst, int R, int C) {
  __shared__ float t[32][33];
  int c0 = blockIdx.x * 32, r0 = blockIdx.y * 32;
  int tx = threadIdx.x & 31, ty = threadIdx.x >> 5;
  #pragma unroll
  for (int i = 0; i < 32; i += 8) {
    int r = r0 + ty + i, c = c0 + tx;
    t[ty + i][tx] = (r < R && c < C) ? src[(size_t)r * C + c] : 0.f;
  }
  __syncthreads();
  #pragma unroll
  for (int i = 0; i < 32; i += 8) {
    int c = c0 + ty + i, r = r0 + tx;
    if (c < C && r < R) dst[(size_t)c * R + r] = f2bf(t[tx][ty + i]);
  }
}

// ---------------- layernorm fp32 -> bf16 (LN1) ----------------
__global__ __launch_bounds__(256) void ln_k(const float* __restrict__ x,
                                            const float* __restrict__ g,
                                            const float* __restrict__ b,
                                            u16* __restrict__ out) {
  int row = blockIdx.x;
  const float* xr = x + (size_t)row * D_;
  float v0 = xr[threadIdx.x], v1 = xr[threadIdx.x + 256], v2 = xr[threadIdx.x + 512];
  float s = v0 + v1 + v2;
  float s2 = v0 * v0 + v1 * v1 + v2 * v2;
  #pragma unroll
  for (int o = 32; o > 0; o >>= 1) {
    s += __shfl_down(s, o, 64);
    s2 += __shfl_down(s2, o, 64);
  }
  __shared__ float a[4], a2[4];
  int wv = threadIdx.x >> 6;
  if ((threadIdx.x & 63) == 0) { a[wv] = s; a2[wv] = s2; }
  __syncthreads();
  s = a[0] + a[1] + a[2] + a[3];
  s2 = a2[0] + a2[1] + a2[2] + a2[3];
  float mean = s * (1.f / 768.f);
  float var = s2 * (1.f / 768.f) - mean * mean;
  float rstd = rsqrtf(var + 1e-5f);
  u16* orow = out + (size_t)row * D_;
  float vv[3] = {v0, v1, v2};
  #pragma unroll
  for (int j = 0; j < 3; ++j) {
    int i = threadIdx.x + j * 256;
    orow[i] = f2bf((vv[j] - mean) * rstd * g[i] + b[i]);
  }
}

// ---------------- x2 = x + O0 + O1; hln = LN(x2) (LN2 fused with partial-O sum) ----------------
__global__ __launch_bounds__(256) void ln2add_k(const float* __restrict__ x,
                                                const u16* __restrict__ O0,
                                                const u16* __restrict__ O1,
                                                const float* __restrict__ g,
                                                const float* __restrict__ b,
                                                float* __restrict__ x2,
                                                u16* __restrict__ out) {
  int row = blockIdx.x;
  const float* xr = x + (size_t)row * D_;
  const u16* o0 = O0 + (size_t)row * D_;
  const u16* o1 = O1 + (size_t)row * D_;
  float vv[3];
  #pragma unroll
  for (int j = 0; j < 3; ++j) {
    int i = threadIdx.x + j * 256;
    vv[j] = xr[i] + bf2f(o0[i]) + bf2f(o1[i]);
  }
  float s = vv[0] + vv[1] + vv[2];
  float s2 = vv[0] * vv[0] + vv[1] * vv[1] + vv[2] * vv[2];
  #pragma unroll
  for (int o = 32; o > 0; o >>= 1) {
    s += __shfl_down(s, o, 64);
    s2 += __shfl_down(s2, o, 64);
  }
  __shared__ float a[4], a2[4];
  int wv = threadIdx.x >> 6;
  if ((threadIdx.x & 63) == 0) { a[wv] = s; a2[wv] = s2; }
  __syncthreads();
  s = a[0] + a[1] + a[2] + a[3];
  s2 = a2[0] + a2[1] + a2[2] + a2[3];
  float mean = s * (1.f / 768.f);
  float var = s2 * (1.f / 768.f) - mean * mean;
  float rstd = rsqrtf(var + 1e-5f);
  float* x2r = x2 + (size_t)row * D_;
  u16* orow = out + (size_t)row * D_;
  #pragma unroll
  for (int j = 0; j < 3; ++j) {
    int i = threadIdx.x + j * 256;
    x2r[i] = vv[j];
    orow[i] = f2bf((vv[j] - mean) * rstd * g[i] + b[i]);
  }
}

// ============ staged 128x128 GEMM core (m97 pattern), K-stride 32 ============
template <int K>
__device__ __forceinline__ void staged_core(const u16* __restrict__ Ab,
                                            const u16* __restrict__ Bb,
                                            u16* As, u16* Bs, f4 acc[4][4]) {
  const int wave = threadIdx.x >> 6, lane = threadIdx.x & 63;
  const int l15 = lane & 15, quad = lane >> 4;
  const int lrow = lane >> 2;
  const int lcol = (lane & 3) * 8;
  const int mw = (wave & 1) * 64, nw = (wave >> 1) * 64;
  for (int k0 = 0; k0 < K; k0 += 32) {
    const u16* ga = Ab + (size_t)(wave * 32 + lrow) * K + k0 + lcol;
    gl_lds16(ga, &As[(wave * 32) * 32]);
    gl_lds16(ga + (size_t)16 * K, &As[(wave * 32 + 16) * 32]);
    const u16* gb = Bb + (size_t)(wave * 32 + lrow) * K + k0 + lcol;
    gl_lds16(gb, &Bs[(wave * 32) * 32]);
    gl_lds16(gb + (size_t)16 * K, &Bs[(wave * 32 + 16) * 32]);
    __syncthreads();
    bf8 a[4], b[4];
    #pragma unroll
    for (int mt = 0; mt < 4; ++mt)
      a[mt] = *reinterpret_cast<const bf8*>(&As[(mw + mt * 16 + l15) * 32 + quad * 8]);
    #pragma unroll
    for (int nt = 0; nt < 4; ++nt)
      b[nt] = *reinterpret_cast<const bf8*>(&Bs[(nw + nt * 16 + l15) * 32 + quad * 8]);
    __builtin_amdgcn_s_setprio(1);
    #pragma unroll
    for (int mt = 0; mt < 4; ++mt)
      #pragma unroll
      for (int nt = 0; nt < 4; ++nt)
        acc[mt][nt] = mfma16(a[mt], b[nt], acc[mt][nt]);
    __builtin_amdgcn_s_setprio(0);
    __syncthreads();
  }
}

// ---------------- QKV GEMM staged ----------------
__global__ __launch_bounds__(256) void gemm_qkv_k(const u16* __restrict__ hln,
                                                  const u16* __restrict__ wT,
                                                  const float* __restrict__ bias,
                                                  u16* __restrict__ Q, u16* __restrict__ Km,
                                                  u16* __restrict__ Vt) {
  __shared__ u16 As[128 * 32], Bs[128 * 32];
  int lin = blockIdx.y * gridDim.x + blockIdx.x;
  int swz = xcd_swz(lin, gridDim.x * gridDim.y);
  int m0 = (swz / gridDim.x) * 128, n0 = (swz % gridDim.x) * 128;
  f4 acc[4][4];
  ZERO44(acc);
  staged_core<768>(hln + (size_t)m0 * 768, wT + (size_t)n0 * 768, As, Bs, acc);
  int wave = threadIdx.x >> 6, lane = threadIdx.x & 63, l15 = lane & 15, quad = lane >> 4;
  int mW = m0 + (wave & 1) * 64, nW = n0 + (wave >> 1) * 64;
  #pragma unroll
  for (int mt = 0; mt < 4; ++mt)
    #pragma unroll
    for (int nt = 0; nt < 4; ++nt)
      #pragma unroll
      for (int r = 0; r < 4; ++r) {
        int m = mW + mt * 16 + quad * 4 + r;
        int n = nW + nt * 16 + l15;
        float v = acc[mt][nt][r] + bias[n];
        u16 bv = f2bf(v);
        int b = m >> 11, p = m & 2047;
        int which = n / 768, hn = n % 768;
        int h = hn >> 6, d = hn & 63;
        if (which == 0)
          Q[((size_t)(b * H_ + h) * P_ + p) * HD_ + d] = bv;
        else if (which == 1)
          Km[((size_t)(b * H_ + h) * P_ + p) * HD_ + d] = bv;
        else
          Vt[((size_t)(b * H_ + h) * HD_ + d) * P_ + p] = bv;
      }
}

// ---------------- FC1 GEMM staged + exact GELU ----------------
__global__ __launch_bounds__(256) void gemm_fc1_k(const u16* __restrict__ A,
                                                  const u16* __restrict__ wT,
                                                  const float* __restrict__ bias,
                                                  u16* __restrict__ out) {
  __shared__ u16 As[128 * 32], Bs[128 * 32];
  int lin = blockIdx.y * gridDim.x + blockIdx.x;
  int swz = xcd_swz(lin, gridDim.x * gridDim.y);
  int m0 = (swz / gridDim.x) * 128, n0 = (swz % gridDim.x) * 128;
  f4 acc[4][4];
  ZERO44(acc);
  staged_core<768>(A + (size_t)m0 * 768, wT + (size_t)n0 * 768, As, Bs, acc);
  int wave = threadIdx.x >> 6, lane = threadIdx.x & 63, l15 = lane & 15, quad = lane >> 4;
  int mW = m0 + (wave & 1) * 64, nW = n0 + (wave >> 1) * 64;
  #pragma unroll
  for (int mt = 0; mt < 4; ++mt)
    #pragma unroll
    for (int nt = 0; nt < 4; ++nt)
      #pragma unroll
      for (int r = 0; r < 4; ++r) {
        int m = mW + mt * 16 + quad * 4 + r;
        int n = nW + nt * 16 + l15;
        float v = acc[mt][nt][r] + bias[n];
        v = 0.5f * v * (1.f + erff(v * 0.70710678f));
        out[(size_t)m * 3072 + n] = f2bf(v);
      }
}

// ---------------- FC2 GEMM staged (BM=128, BN=64), +bias +residual -> fp32 ----------------
__global__ __launch_bounds__(256) void gemm_fc2_k(const u16* __restrict__ A,
                                                  const u16* __restrict__ wT,
                                                  const float* __restrict__ bias,
                                                  const float* __restrict__ resid,
                                                  float* __restrict__ out) {
  __shared__ u16 As[128 * 32], Bs[64 * 32];
  int wave = threadIdx.x >> 6, lane = threadIdx.x & 63, l15 = lane & 15, quad = lane >> 4;
  int lrow = lane >> 2, lcol = (lane & 3) * 8;
  int lin = blockIdx.y * gridDim.x + blockIdx.x;
  int swz = xcd_swz(lin, gridDim.x * gridDim.y);
  int m0 = (swz / gridDim.x) * 128, n0 = (swz % gridDim.x) * 64;
  const u16* Ab = A + (size_t)m0 * 3072;
  const u16* Bb = wT + (size_t)n0 * 3072;
  int mw = (wave & 1) * 64, nw = (wave >> 1) * 32;
  f4 acc[4][2];
  #pragma unroll
  for (int i = 0; i < 4; ++i)
    #pragma unroll
    for (int j = 0; j < 2; ++j) acc[i][j] = f4{0.f, 0.f, 0.f, 0.f};
  for (int k0 = 0; k0 < 3072; k0 += 32) {
    const u16* ga = Ab + (size_t)(wave * 32 + lrow) * 3072 + k0 + lcol;
    gl_lds16(ga, &As[(wave * 32) * 32]);
    gl_lds16(ga + (size_t)16 * 3072, &As[(wave * 32 + 16) * 32]);
    const u16* gb = Bb + (size_t)(wave * 16 + lrow) * 3072 + k0 + lcol;
    gl_lds16(gb, &Bs[(wave * 16) * 32]);
    __syncthreads();
    bf8 a[4], b[2];
    #pragma unroll
    for (int mt = 0; mt < 4; ++mt)
      a[mt] = *reinterpret_cast<const bf8*>(&As[(mw + mt * 16 + l15) * 32 + quad * 8]);
    #pragma unroll
    for (int nt = 0; nt < 2; ++nt)
      b[nt] = *reinterpret_cast<const bf8*>(&Bs[(nw + nt * 16 + l15) * 32 + quad * 8]);
    __builtin_amdgcn_s_setprio(1);
    #pragma unroll
    for (int mt = 0; mt < 4; ++mt)
      #pragma unroll
      for (int nt = 0; nt < 2; ++nt)
        acc[mt][nt] = mfma16(a[mt], b[nt], acc[mt][nt]);
    __builtin_amdgcn_s_setprio(0);
    __syncthreads();
  }
  int mW = m0 + mw, nW = n0 + nw;
  #pragma unroll
  for (int mt = 0; mt < 4; ++mt)
    #pragma unroll
    for (int nt = 0; nt < 2; ++nt)
      #pragma unroll
      for (int r = 0; r < 4; ++r) {
        int m = mW + mt * 16 + quad * 4 + r;
        int n = nW + nt * 16 + l15;
        size_t idx = (size_t)m * 768 + n;
        out[idx] = acc[mt][nt][r] + bias[n] + resid[idx];
      }
}

// ======== fused attention v8: heads-softmax, qBLK=64 (half the barriers) ========
// Grid: 256 blocks, 1/CU. g=id&7 -> XCD; (b,qs)=g so each XCD streams ONE (b,qs)
// K/V sequence (L2-resident). 768 threads = 12 waves = 12 heads.
// Dynamic LDS 119 KB: E[12][64][68] bf16 (104448 B) + R[64][68] f32 (17408 B).
// Per 64-wide q-tile (16 tiles, 2 barriers each -> 32 barrier-pairs vs v7's 64):
//   [ K frags (4x16q); S^T (4 mt subtiles) + exp -> E[w]; V-half0 loads ]
//   b1; [ R[p][q] = 1/sum_h E : 1024 f4 chunks over 768 threads ]
//   b2; [ PV half0 (E cols 0..31); V-half1 loads; PV half1 (cols 32..63) ]
// Register budget: unified VGPR+AGPR <= ~170/wave at 3 waves/SIMD; oacc=64 AGPR,
// VGPR peak (qf32+kf32+s16+addr) ~90 -> no spill expected (WRITE_SIZE sentinel).
__global__ __launch_bounds__(768) void attn_fused_k(const u16* __restrict__ Q,
                                                    const u16* __restrict__ Km,
                                                    const u16* __restrict__ Vt,
                                                    u16* __restrict__ O0,
                                                    u16* __restrict__ O1) {
  extern __shared__ __align__(16) char smem[];
  u16(*E)[64][68] = reinterpret_cast<u16(*)[64][68]>(smem);        // [12][64][68]
  float(*R)[68] = reinterpret_cast<float(*)[68]>(smem + 104448);   // [64][68]

  int id = blockIdx.x;
  int g = id & 7, pt = id >> 3;
  int b = g >> 1, qs = g & 1;
  int w = threadIdx.x >> 6, lane = threadIdx.x & 63, l15 = lane & 15, quad = lane >> 4;

  const u16* Qp = Q + ((size_t)(b * H_ + w) * P_ + pt * 64) * HD_;
  const u16* Kbase = Km + ((size_t)(b * H_ + w) * P_ + qs * 1024) * HD_;
  const u16* Vbase = Vt + (size_t)(b * H_ + w) * HD_ * P_ + qs * 1024;

  // Q fragments: 64 p-rows of this wave's head (persist across all q-tiles)
  bf8 qf[4][2];
  #pragma unroll
  for (int nt = 0; nt < 4; ++nt)
    #pragma unroll
    for (int ks = 0; ks < 2; ++ks)
      qf[nt][ks] = *reinterpret_cast<const bf8*>(Qp + (size_t)(nt * 16 + l15) * HD_ + ks * 32 + quad * 8);

  f4 oacc[4][4];  // O^T: d (4x16) x p (4x16)
  ZERO44(oacc);

  for (int qt = 0; qt < 16; ++qt) {
    const u16* Kp = Kbase + (size_t)qt * 64 * HD_;
    // K fragments for this 64-q tile (4 x 16 q-rows)
    bf8 kf[4][2];
    #pragma unroll
    for (int mt = 0; mt < 4; ++mt)
      #pragma unroll
      for (int ks = 0; ks < 2; ++ks)
        kf[mt][ks] = *reinterpret_cast<const bf8*>(Kp + (size_t)(mt * 16 + l15) * HD_ + ks * 32 + quad * 8);
    // S^T + exp -> E[w], one mt (16 q-rows) at a time
    #pragma unroll
    for (int mt = 0; mt < 4; ++mt) {
      f4 s[4];
      #pragma unroll
      for (int nt = 0; nt < 4; ++nt) s[nt] = f4{0.f, 0.f, 0.f, 0.f};
      __builtin_amdgcn_s_setprio(1);
      #pragma unroll
      for (int nt = 0; nt < 4; ++nt) {
        s[nt] = mfma16(kf[mt][0], qf[nt][0], s[nt]);
        s[nt] = mfma16(kf[mt][1], qf[nt][1], s[nt]);
      }
      __builtin_amdgcn_s_setprio(0);
      #pragma unroll
      for (int nt = 0; nt < 4; ++nt) {
        f4 e;
        #pragma unroll
        for (int r = 0; r < 4; ++r) e[r] = __builtin_amdgcn_exp2f(s[nt][r] * EXPC_);
        *reinterpret_cast<uint2*>(&E[w][nt * 16 + l15][mt * 16 + quad * 4]) = pack4(e);
      }
    }
    // V half-0 fragments issued now, consumed after b2 (latency under R phase)
    bf8 vf[4];
    #pragma unroll
    for (int dt = 0; dt < 4; ++dt)
      vf[dt] = *reinterpret_cast<const bf8*>(Vbase + (size_t)(dt * 16 + l15) * P_ + qt * 64 + quad * 8);
    __syncthreads();  // b1: E(qt) complete
    // R[p][q] = 1 / sum_h E[h][p][q]  (1024 f4 chunks over 768 threads)
    for (int c = threadIdx.x; c < 1024; c += 768) {
      int p = c >> 4, qc = (c & 15) * 4;
      f4 sum = {0.f, 0.f, 0.f, 0.f};
      #pragma unroll
      for (int h = 0; h < 12; ++h)
        sum += unpack4(*reinterpret_cast<const ushort4*>(&E[h][p][qc]));
      f4 rc;
      #pragma unroll
      for (int c2 = 0; c2 < 4; ++c2) rc[c2] = __builtin_amdgcn_rcpf(sum[c2]);
      *reinterpret_cast<f4*>(&R[p][qc]) = rc;
    }
    __syncthreads();  // b2: R ready
    // PV half 0: O^T += V^T(q 0..31) @ (E*R)(q 0..31)
    #pragma unroll
    for (int pi = 0; pi < 4; ++pi) {
      int pp = pi * 16 + l15;
      uint2 e0 = *reinterpret_cast<const uint2*>(&E[w][pp][quad * 8]);
      uint2 e1 = *reinterpret_cast<const uint2*>(&E[w][pp][quad * 8 + 4]);
      f4 r0 = *reinterpret_cast<const f4*>(&R[pp][quad * 8]);
      f4 r1 = *reinterpret_cast<const f4*>(&R[pp][quad * 8 + 4]);
      bf8 af = mkbf8(unp2(e0) * r0, unp2(e1) * r1);
      __builtin_amdgcn_s_setprio(1);
      #pragma unroll
      for (int dt = 0; dt < 4; ++dt)
        oacc[dt][pi] = mfma16(vf[dt], af, oacc[dt][pi]);
      __builtin_amdgcn_s_setprio(0);
    }
    // V half-1 fragments (latency under half-0 MFMAs above)
    #pragma unroll
    for (int dt = 0; dt < 4; ++dt)
      vf[dt] = *reinterpret_cast<const bf8*>(Vbase + (size_t)(dt * 16 + l15) * P_ + qt * 64 + 32 + quad * 8);
    // PV half 1: O^T += V^T(q 32..63) @ (E*R)(q 32..63)
    #pragma unroll
    for (int pi = 0; pi < 4; ++pi) {
      int pp = pi * 16 + l15;
      uint2 e0 = *reinterpret_cast<const uint2*>(&E[w][pp][32 + quad * 8]);
      uint2 e1 = *reinterpret_cast<const uint2*>(&E[w][pp][32 + quad * 8 + 4]);
      f4 r0 = *reinterpret_cast<const f4*>(&R[pp][32 + quad * 8]);
      f4 r1 = *reinterpret_cast<const f4*>(&R[pp][32 + quad * 8 + 4]);
      bf8 af = mkbf8(unp2(e0) * r0, unp2(e1) * r1);
      __builtin_amdgcn_s_setprio(1);
      #pragma unroll
      for (int dt = 0; dt < 4; ++dt)
        oacc[dt][pi] = mfma16(vf[dt], af, oacc[dt][pi]);
      __builtin_amdgcn_s_setprio(0);
    }
    // E[w]/R hazards: E[w] single-writer/single-reader per plane across waves for
    // S-writes (own plane) vs R-reads (guarded by b1/b2 of this and next tile).
  }
  __syncthreads();
  // epilogue: stage O^T (bf16) through LDS (alias smem as [6][64][72]) in 2 head-phases
  u16(*Os)[64][72] = reinterpret_cast<u16(*)[64][72]>(smem);
  u16* Op = qs ? O1 : O0;
  #pragma unroll
  for (int hh = 0; hh < 2; ++hh) {
    if (w >= hh * 6 && w < hh * 6 + 6) {
      int wp = w - hh * 6;
      #pragma unroll
      for (int dt = 0; dt < 4; ++dt)
        #pragma unroll
        for (int pi = 0; pi < 4; ++pi)
          *reinterpret_cast<uint2*>(&Os[wp][pi * 16 + l15][dt * 16 + quad * 4]) = pack4(oacc[dt][pi]);
    }
    __syncthreads();
    #pragma unroll
    for (int j = 0; j < 4; ++j) {
      int c = threadIdx.x + j * 768;   // 0..3071
      int p = c / 48, m = c % 48;
      int hp = m >> 3, d = (m & 7) * 8;
      uint4 val = *reinterpret_cast<const uint4*>(&Os[hp][p][d]);
      size_t go = (((size_t)b * P_) + pt * 64 + p) * D_ + (hh * 6 + hp) * 64 + d;
      *reinterpret_cast<uint4*>(Op + go) = val;
    }
    __syncthreads();
  }
}

extern "C" void kernel_launch(void* const* d_in, const int* in_sizes, int n_in,
                              void* d_out, int out_size, void* d_ws, size_t ws_size,
                              hipStream_t stream) {
  const float* x = (const float*)d_in[0];
  const float* ln1w = (const float*)d_in[1];
  const float* ln1b = (const float*)d_in[2];
  const float* wqkv = (const float*)d_in[3];
  const float* bqkv = (const float*)d_in[4];
  const float* ln2w = (const float*)d_in[5];
  const float* ln2b = (const float*)d_in[6];
  const float* wfc1 = (const float*)d_in[7];
  const float* bfc1 = (const float*)d_in[8];
  const float* wfc2 = (const float*)d_in[9];
  const float* bfc2 = (const float*)d_in[10];
  float* out = (float*)d_out;

  char* ws = (char*)d_ws;
  size_t off = 0;
  auto alloc = [&](size_t bytes) -> void* {
    void* p = ws + off;
    off += (bytes + 255) & ~(size_t)255;
    return p;
  };
  u16* hln = (u16*)alloc((size_t)8192 * 768 * 2);
  u16* wqkvT = (u16*)alloc((size_t)2304 * 768 * 2);
  u16* wfc1T = (u16*)alloc((size_t)3072 * 768 * 2);
  u16* wfc2T = (u16*)alloc((size_t)768 * 3072 * 2);
  u16* Qb = (u16*)alloc((size_t)B_ * H_ * P_ * HD_ * 2);
  u16* Kb = (u16*)alloc((size_t)B_ * H_ * P_ * HD_ * 2);
  u16* Vtb = (u16*)alloc((size_t)B_ * H_ * HD_ * P_ * 2);
  float* x2 = (float*)alloc((size_t)8192 * 768 * 4);
  u16* O0 = (u16*)alloc((size_t)8192 * 768 * 2);
  u16* O1 = (u16*)alloc((size_t)8192 * 768 * 2);
  u16* gbuf = (u16*)alloc((size_t)8192 * 3072 * 2);

  // allow 119 KB dynamic LDS for the attention kernel (gfx950: 160 KB/CU)
  hipFuncSetAttribute((const void*)attn_fused_k,
                      hipFuncAttributeMaxDynamicSharedMemorySize, 121856);

  tcast_k<<<dim3(72, 24), 256, 0, stream>>>(wqkv, wqkvT, 768, 2304);
  tcast_k<<<dim3(96, 24), 256, 0, stream>>>(wfc1, wfc1T, 768, 3072);
  tcast_k<<<dim3(24, 96), 256, 0, stream>>>(wfc2, wfc2T, 3072, 768);
  ln_k<<<8192, 256, 0, stream>>>(x, ln1w, ln1b, hln);
  gemm_qkv_k<<<dim3(18, 64), 256, 0, stream>>>(hln, wqkvT, bqkv, Qb, Kb, Vtb);
  attn_fused_k<<<256, 768, 121856, stream>>>(Qb, Kb, Vtb, O0, O1);
  ln2add_k<<<8192, 256, 0, stream>>>(x, O0, O1, ln2w, ln2b, x2, hln);
  gemm_fc1_k<<<dim3(24, 64), 256, 0, stream>>>(hln, wfc1T, bfc1, gbuf);
  gemm_fc2_k<<<dim3(12, 64), 256, 0, stream>>>(gbuf, wfc2T, bfc2, x2, out);
}